// Round 10
// baseline (301.885 us; speedup 1.0000x reference)
//
#include <hip/hip_runtime.h>
#include <hip/hip_bf16.h>
#include <cstdint>
#include <cstddef>

#define BDIM 32768
#define IDIM 512
#define ODIM 512
#define KDIM 1024   // I+O
#define NDIM 2048   // 4*O

typedef __attribute__((ext_vector_type(8))) __bf16 bf16x8;
typedef __attribute__((ext_vector_type(4))) float f32x4;
typedef __attribute__((ext_vector_type(8))) unsigned short u16x8;

__device__ __forceinline__ unsigned short f2bf(float x) {
  union { float f; uint32_t u; } v; v.f = x;
  uint32_t r = v.u + 0x7FFFu + ((v.u >> 16) & 1u);  // RNE
  return (unsigned short)(r >> 16);
}

__device__ __forceinline__ float bf2f(unsigned short s) {
  union { uint32_t u; float f; } v; v.u = ((uint32_t)s) << 16;
  return v.f;
}

// ---------------- pack kernels: f32 -> bf16 ----------------

__global__ __launch_bounds__(256) void pack_a_kernel(const float* __restrict__ in,
                                                     const float* __restrict__ h,
                                                     unsigned short* __restrict__ A) {
  size_t t = (size_t)blockIdx.x * 256 + threadIdx.x;
  size_t e = t * 8;
  size_t b = e >> 10;
  int col = (int)(e & 1023);
  const float* src = (col < IDIM) ? (in + b * IDIM + col)
                                  : (h + b * ODIM + (col - IDIM));
  float4 v0 = ((const float4*)src)[0];
  float4 v1 = ((const float4*)src)[1];
  u16x8 r;
  r[0] = f2bf(v0.x); r[1] = f2bf(v0.y); r[2] = f2bf(v0.z); r[3] = f2bf(v0.w);
  r[4] = f2bf(v1.x); r[5] = f2bf(v1.y); r[6] = f2bf(v1.z); r[7] = f2bf(v1.w);
  *(u16x8*)(A + e) = r;
}

__global__ __launch_bounds__(256) void pack_w_kernel(const float* __restrict__ Wsrc,
                                                     unsigned short* __restrict__ Wb) {
  size_t t = (size_t)blockIdx.x * 256 + threadIdx.x;
  size_t e = t * 8;
  float4 v0 = ((const float4*)(Wsrc + e))[0];
  float4 v1 = ((const float4*)(Wsrc + e))[1];
  u16x8 r;
  r[0] = f2bf(v0.x); r[1] = f2bf(v0.y); r[2] = f2bf(v0.z); r[3] = f2bf(v0.w);
  r[4] = f2bf(v1.x); r[5] = f2bf(v1.y); r[6] = f2bf(v1.z); r[7] = f2bf(v1.w);
  *(u16x8*)(Wb + e) = r;
}

// ---------------- GEMM: 256x256 tile, BK=32, dbuf-2 (64KB), 2 blocks/CU ----------------
// R10 theory: all prior schedules (R3/R5/R8/R9) pin at MfmaUtil 35-39% because
// 128KB LDS => 1 block/CU => 2 barrier-lockstepped waves/SIMD; the matrix pipe
// idles during every read/wait window. Fix = occupancy: 64KB LDS => 2
// INDEPENDENT blocks/CU; block B's waves issue MFMA while block A stalls.
// Fragment-ordered LDS (verified 0 conflicts R4-R9): frag = 64 lanes x 16B
// contiguous; per 32KB buffer: A = 16 frags x 1KB, B at +16384.
// dbuf-2 safety: tile-t top {VMW(0); BAR} retires this wave's tile-t loads
// AND guarantees all waves finished reading buf^1 (reads lgkm-drained before
// their last MFMA of t-1) -> staging buf^1 during tile t is safe.

#define BUFSZ 32768

#define BAR() do { asm volatile("" ::: "memory"); __builtin_amdgcn_s_barrier(); asm volatile("" ::: "memory"); } while (0)
#define VMW(n) asm volatile("s_waitcnt vmcnt(" #n ")" ::: "memory")
#define LGKM0() do { asm volatile("s_waitcnt lgkmcnt(0)" ::: "memory"); __builtin_amdgcn_sched_barrier(0); } while (0)

__device__ __forceinline__ void gll16(const unsigned short* src, char* ldsdst) {
  __builtin_amdgcn_global_load_lds(
      (const __attribute__((address_space(1))) void*)src,
      (__attribute__((address_space(3))) void*)ldsdst, 16, 0, 0);
}

template<int CBUF, bool STG>
__device__ __forceinline__ void ktile32(char* smem, const char* aRd, const char* bRd,
                                        const unsigned short* pA0, const unsigned short* pA1,
                                        const unsigned short* pB0, const unsigned short* pB1,
                                        int stOff, f32x4 (&acc)[8][4]) {
  constexpr int CB = CBUF * BUFSZ;
  constexpr int SB = (CBUF ^ 1) * BUFSZ;
  bf16x8 a[4], qf[4];

  VMW(0);   // tile t's staged data landed (issued during t-1)
  BAR();    // + all waves done reading buf^1 -> safe to overwrite

  // ---- phase 0: read A mf0-3 + B nj0-3; stage A-frags of tile t+1 ----
#pragma unroll
  for (int i = 0; i < 4; ++i) a[i] = *(const bf16x8*)(aRd + CB + i * 1024);
#pragma unroll
  for (int j = 0; j < 4; ++j) qf[j] = *(const bf16x8*)(bRd + CB + j * 1024);
  if (STG) {
    gll16(pA0, smem + SB + stOff);
    gll16(pA1, smem + SB + 8192 + stOff);
  }
  BAR(); LGKM0();
  __builtin_amdgcn_s_setprio(1);
#pragma unroll
  for (int i = 0; i < 4; ++i)
#pragma unroll
    for (int j = 0; j < 4; ++j)
      acc[i][j] = __builtin_amdgcn_mfma_f32_16x16x32_bf16(a[i], qf[j], acc[i][j], 0, 0, 0);
  __builtin_amdgcn_s_setprio(0);
  __builtin_amdgcn_sched_barrier(0);
  BAR();

  // ---- phase 1: read A mf4-7; stage B-frags of tile t+1 ----
#pragma unroll
  for (int i = 0; i < 4; ++i) a[i] = *(const bf16x8*)(aRd + CB + (4 + i) * 1024);
  if (STG) {
    gll16(pB0, smem + SB + 16384 + stOff);
    gll16(pB1, smem + SB + 24576 + stOff);
  }
  BAR(); LGKM0();
  __builtin_amdgcn_s_setprio(1);
#pragma unroll
  for (int i = 0; i < 4; ++i)
#pragma unroll
    for (int j = 0; j < 4; ++j)
      acc[4 + i][j] = __builtin_amdgcn_mfma_f32_16x16x32_bf16(a[i], qf[j], acc[4 + i][j], 0, 0, 0);
  __builtin_amdgcn_s_setprio(0);
  __builtin_amdgcn_sched_barrier(0);
  // no trailing barrier: next tile's top barrier covers it
}

__global__ __launch_bounds__(512, 2) void gemm_kernel(const unsigned short* __restrict__ A,
                                                      const unsigned short* __restrict__ Bt,
                                                      unsigned short* __restrict__ Cz) {
  extern __shared__ char smem[];
  const int tid = threadIdx.x;
  const int w = tid >> 6;
  const int lane = tid & 63;

  // XCD swizzle: each XCD gets a 16-mtile x 8-ntile chunk (B panel L2-resident)
  const int bid = blockIdx.x;                       // 0..1023
  const int swz = (bid & 7) * 128 + (bid >> 3);
  const int m0 = (swz >> 3) * 256;
  const int n0 = (swz & 7) * 256;

  const int wm = (w >> 2) * 128;   // 2 M-wave-rows
  const int wn = (w & 3) * 64;     // 4 N-wave-cols
  const int lrow = lane & 15;
  const int lk = (lane >> 4) * 8;

  // fragment read bases (linear within frag -> conflict-free)
  const char* aRd = smem + (w >> 2) * 8192 + lane * 16;          // A frags (w>>2)*8 + i
  const char* bRd = smem + 16384 + (w & 3) * 4096 + lane * 16;   // B frags (w&3)*4 + j
  const int stOff = w * 1024 + lane * 16;

  // staging sources: wave w stages A-frags {w, w+8}, B-frags {w, w+8}
  const unsigned short* pA0 = A  + (size_t)(m0 + w * 16       + lrow) * KDIM + lk;
  const unsigned short* pA1 = A  + (size_t)(m0 + (8 + w) * 16 + lrow) * KDIM + lk;
  const unsigned short* pB0 = Bt + (size_t)(n0 + w * 16       + lrow) * KDIM + lk;
  const unsigned short* pB1 = Bt + (size_t)(n0 + (8 + w) * 16 + lrow) * KDIM + lk;

  f32x4 acc[8][4] = {};

  // prologue: stage tile 0 into buf0
  gll16(pA0, smem + stOff);
  gll16(pA1, smem + 8192 + stOff);
  gll16(pB0, smem + 16384 + stOff);
  gll16(pB1, smem + 24576 + stOff);
  pA0 += 32; pA1 += 32; pB0 += 32; pB1 += 32;  // -> tile 1

  // main loop: 32 K-tiles; tile t computes buf t&1, stages t+1 into buf (t+1)&1
  for (int tt = 0; tt < 15; ++tt) {
    ktile32<0, true>(smem, aRd, bRd, pA0, pA1, pB0, pB1, stOff, acc);
    pA0 += 32; pA1 += 32; pB0 += 32; pB1 += 32;
    ktile32<1, true>(smem, aRd, bRd, pA0, pA1, pB0, pB1, stOff, acc);
    pA0 += 32; pA1 += 32; pB0 += 32; pB1 += 32;
  }
  ktile32<0, true >(smem, aRd, bRd, pA0, pA1, pB0, pB1, stOff, acc);  // t30 stages t31
  ktile32<1, false>(smem, aRd, bRd, pA0, pA1, pB0, pB1, stOff, acc);  // t31

  // epilogue: C/D layout col = lane&15, row = (lane>>4)*4 + r
#pragma unroll
  for (int mi = 0; mi < 8; ++mi) {
#pragma unroll
    for (int ni = 0; ni < 4; ++ni) {
#pragma unroll
      for (int r = 0; r < 4; ++r) {
        const int row = m0 + wm + mi * 16 + (lane >> 4) * 4 + r;
        const int col = n0 + wn + ni * 16 + lrow;
        Cz[(size_t)row * NDIM + col] = f2bf(acc[mi][ni][r]);
      }
    }
  }
}

// ---------------- LayerNorm + gates ----------------

__global__ __launch_bounds__(256) void ln_gate_kernel(const unsigned short* __restrict__ z,
                                                      const float* __restrict__ c,
                                                      const float* __restrict__ gamma,
                                                      const float* __restrict__ beta,
                                                      float* __restrict__ out) {
  __shared__ float rowbuf[4][NDIM];  // 32 KB
  const int wave = threadIdx.x >> 6;
  const int lane = threadIdx.x & 63;
  const int row = blockIdx.x * 4 + wave;
  const unsigned short* zr = z + (size_t)row * NDIM;

  float s = 0.f, ss = 0.f;
#pragma unroll
  for (int j = 0; j < 4; ++j) {
    const int chunk = j * 64 + lane;
    u16x8 v = *(const u16x8*)(zr + chunk * 8);
    float f[8];
#pragma unroll
    for (int i2 = 0; i2 < 8; ++i2) {
      f[i2] = bf2f(v[i2]);
      s += f[i2];
      ss += f[i2] * f[i2];
    }
    float4* dst = (float4*)&rowbuf[wave][chunk * 8];
    dst[0] = make_float4(f[0], f[1], f[2], f[3]);
    dst[1] = make_float4(f[4], f[5], f[6], f[7]);
  }
#pragma unroll
  for (int off = 32; off > 0; off >>= 1) {
    s += __shfl_xor(s, off, 64);
    ss += __shfl_xor(ss, off, 64);
  }
  const float mean = s * (1.f / (float)NDIM);
  const float var = ss * (1.f / (float)NDIM) - mean * mean;
  const float inv = rsqrtf(var + 1e-5f);

  float* out_o = out + (size_t)row * ODIM;
  float* out_c = out + (size_t)BDIM * ODIM + (size_t)row * ODIM;
  const float* crow = c + (size_t)row * ODIM;

#pragma unroll
  for (int j = 0; j < 8; ++j) {
    const int o = j * 64 + lane;
    float zn[4];
#pragma unroll
    for (int g = 0; g < 4; ++g) {
      float v = (rowbuf[wave][g * ODIM + o] - mean) * inv;
      zn[g] = v * gamma[g * ODIM + o] + beta[g * ODIM + o];
    }
    const float fg = 1.f / (1.f + expf(-zn[0]));
    const float ig = 1.f / (1.f + expf(-zn[1]));
    const float og = 1.f / (1.f + expf(-zn[2]));
    const float x = zn[3];
    const float hs = 0.5f * x * (1.f + erff(x * 0.70710678118654752f));
    const float cc = fg * crow[o] + ig * hs;
    out_c[o] = cc;
    out_o[o] = og * cc;
  }
}

// ---------------- launch ----------------

extern "C" void kernel_launch(void* const* d_in, const int* in_sizes, int n_in,
                              void* d_out, int out_size, void* d_ws, size_t ws_size,
                              hipStream_t stream) {
  const float* input = (const float*)d_in[0];
  const float* h     = (const float*)d_in[1];
  const float* c     = (const float*)d_in[2];
  const float* W     = (const float*)d_in[3];
  const float* gamma = (const float*)d_in[4];
  const float* beta  = (const float*)d_in[5];

  unsigned short* A  = (unsigned short*)d_ws;                 // [32768,1024] bf16
  unsigned short* Wb = A + (size_t)BDIM * KDIM;               // [2048,1024] bf16
  unsigned short* z  = Wb + (size_t)NDIM * KDIM;              // [32768,2048] bf16
  float* out = (float*)d_out;

  hipFuncSetAttribute((const void*)gemm_kernel,
                      hipFuncAttributeMaxDynamicSharedMemorySize, 65536);

  pack_a_kernel<<<(BDIM * KDIM / 8) / 256, 256, 0, stream>>>(input, h, A);
  pack_w_kernel<<<(NDIM * KDIM / 8) / 256, 256, 0, stream>>>(W, Wb);
  gemm_kernel<<<dim3((BDIM / 256) * (NDIM / 256)), 512, 65536, stream>>>(A, Wb, z);
  ln_gate_kernel<<<BDIM / 4, 256, 0, stream>>>(z, c, gamma, beta, out);
}